// Round 9
// baseline (72.546 us; speedup 1.0000x reference)
//
#include <hip/hip_runtime.h>

#define NUM_NODES 100000
#define INPUT_DIM 256
#define NUM_BAGS  2048
#define BAG_SIZE  64
#define N_EDGES   3200000
#define NQUAD     (N_EDGES / 4)   // 800000

// dynamic-LDS hist path: 4 partitions x 25000 nodes (100 KB LDS/block)
#define NPP4      25000
#define NSLICE4   64              // grid = 4 * 64 = 256 blocks
// static fallback path (R8): 8 partitions x 12500 nodes (50 KB)
#define NPP8      12500
#define NSLICE8   32

typedef unsigned int u32;

// Pass A: materialize per-edge weights ONCE: w[e] = nw[nbr[e]].
__global__ void __launch_bounds__(256)
mat_w(const int* __restrict__ edge_nbr, const float* __restrict__ nw,
      float* __restrict__ w) {
    const int q = blockIdx.x * 256 + threadIdx.x;    // one int4 quad / thread
    const int4 n4 = ((const int4*)edge_nbr)[q];
    float4 o;
    o.x = nw[n4.x];
    o.y = nw[n4.y];
    o.z = nw[n4.z];
    o.w = nw[n4.w];
    ((float4*)w)[q] = o;
}

// Pass B (main): partitioned LDS histogram, 100 KB dynamic LDS -> P=4,
// rescan factor 4 (halved vs R8). Block bits: [2:0]=r, [4:3]=p, [7:5]=b_hi;
// slice b = r | b_hi<<3, so the 4 partition-blocks of a slice are congruent
// mod 8 (same XCD if dispatch is %8 round-robin — pure upside if true).
// All global reads coalesced; one predicated ds_add per edge; NT flush.
__global__ void __launch_bounds__(1024)
hist4(const int* __restrict__ edge_src, const float* __restrict__ w,
      float* __restrict__ rep) {               // [NSLICE4][NUM_NODES]
    extern __shared__ float hist[];            // NPP4 floats = 100 KB
    const int i    = blockIdx.x;
    const int r    = i & 7;
    const int p    = (i >> 3) & 3;
    const int b    = r | ((i >> 5) << 3);      // 0..63
    const int base = p * NPP4;

    for (int j = threadIdx.x; j < NPP4; j += 1024) hist[j] = 0.f;
    __syncthreads();

    const int per = NQUAD / NSLICE4;           // 12500 quads / slice
    const int lo  = b * per;
    const int hi  = lo + per;
    for (int q = lo + (int)threadIdx.x; q < hi; q += 1024) {
        const int4   s4 = ((const int4*)edge_src)[q];
        const float4 w4 = ((const float4*)w)[q];
#define EDGE(S, W)                                               \
        {                                                        \
            const u32 rel = (u32)((S) - base);                   \
            if (rel < (u32)NPP4) atomicAdd(&hist[rel], (W));     \
        }
        EDGE(s4.x, w4.x)
        EDGE(s4.y, w4.y)
        EDGE(s4.z, w4.z)
        EDGE(s4.w, w4.w)
#undef EDGE
    }
    __syncthreads();

    float* dst = rep + (size_t)b * NUM_NODES + base;
    for (int j = threadIdx.x; j < NPP4; j += 1024)
        __builtin_nontemporal_store(hist[j], &dst[j]);
}

// Pass B (fallback, static 50 KB LDS): R8 structure, P=8.
__global__ void __launch_bounds__(1024)
hist8(const int* __restrict__ edge_src, const float* __restrict__ w,
      float* __restrict__ rep) {               // [NSLICE8][NUM_NODES]
    __shared__ float hist[NPP8];
    const int i    = blockIdx.x;
    const int r    = i & 7;
    const int p    = (i >> 3) & 7;
    const int b    = r | ((i >> 6) << 3);
    const int base = p * NPP8;

    for (int j = threadIdx.x; j < NPP8; j += 1024) hist[j] = 0.f;
    __syncthreads();

    const int per = NQUAD / NSLICE8;
    const int lo  = b * per;
    const int hi  = lo + per;
    for (int q = lo + (int)threadIdx.x; q < hi; q += 1024) {
        const int4   s4 = ((const int4*)edge_src)[q];
        const float4 w4 = ((const float4*)w)[q];
#define EDGE(S, W)                                               \
        {                                                        \
            const u32 rel = (u32)((S) - base);                   \
            if (rel < (u32)NPP8) atomicAdd(&hist[rel], (W));     \
        }
        EDGE(s4.x, w4.x)
        EDGE(s4.y, w4.y)
        EDGE(s4.z, w4.z)
        EDGE(s4.w, w4.w)
#undef EDGE
    }
    __syncthreads();

    float* dst = rep + (size_t)b * NUM_NODES + base;
    for (int j = threadIdx.x; j < NPP8; j += 1024)
        __builtin_nontemporal_store(hist[j], &dst[j]);
}

// Pass 1b: nbr_sum[n] = (sum > 0) ? sum : 1.0  (scalar, coalesced; NSL slices)
template <int NSL>
__global__ void __launch_bounds__(256)
reduce_rep(const float* __restrict__ rep, float* __restrict__ nbr_sum) {
    const int i = blockIdx.x * 256 + threadIdx.x;
    if (i >= NUM_NODES) return;
    float a = 0.f;
    #pragma unroll 8
    for (int r = 0; r < NSL; ++r)
        a += rep[(size_t)r * NUM_NODES + i];
    nbr_sum[i] = a > 0.f ? a : 1.0f;
}

// Pass 2a: h[n] = theta . x[n] — dense coalesced GEMV (102 MB streamed once).
__global__ void __launch_bounds__(256)
gemv_h(const float* __restrict__ x, const float* __restrict__ theta,
       float* __restrict__ h) {
    const int lane = threadIdx.x & 63;
    const int wave = threadIdx.x >> 6;
    const float4 tw = *reinterpret_cast<const float4*>(&theta[lane * 4]);
    const int stride = gridDim.x * 4;
    for (int row = blockIdx.x * 4 + wave; row < NUM_NODES; row += stride) {
        const float4 xv =
            *reinterpret_cast<const float4*>(&x[(size_t)row * INPUT_DIM + lane * 4]);
        float d = xv.x * tw.x + xv.y * tw.y + xv.z * tw.z + xv.w * tw.w;
        #pragma unroll
        for (int off = 32; off >= 1; off >>= 1)
            d += __shfl_xor(d, off);
        if (lane == 0) h[row] = d;
    }
}

// Pass 2b: out[bag] = sum_item h[idx] * nbr_sum[idx] * alpha
__global__ void __launch_bounds__(256)
bag_final(const int* __restrict__ bags, const float* __restrict__ alpha,
          const float* __restrict__ h, const float* __restrict__ ns,
          float* __restrict__ out) {
    const int bag  = blockIdx.x * 4 + (threadIdx.x >> 6);
    const int lane = threadIdx.x & 63;
    const int idx  = bags[bag * BAG_SIZE + lane];
    float v = h[idx] * ns[idx] * alpha[bag * BAG_SIZE + lane];
    #pragma unroll
    for (int off = 32; off >= 1; off >>= 1)
        v += __shfl_xor(v, off);
    if (lane == 0) out[bag] = v;
}

// Tiny-ws fallback: plain device atomics.
__global__ void __launch_bounds__(256)
edge_atomic(const int* __restrict__ edge_src, const int* __restrict__ edge_nbr,
            const float* __restrict__ nw, float* __restrict__ nbr_sum) {
    const int t = blockIdx.x * blockDim.x + threadIdx.x;
    const int4 s4 = ((const int4*)edge_src)[t];
    const int4 n4 = ((const int4*)edge_nbr)[t];
    atomicAdd(&nbr_sum[s4.x], nw[n4.x]);
    atomicAdd(&nbr_sum[s4.y], nw[n4.y]);
    atomicAdd(&nbr_sum[s4.z], nw[n4.z]);
    atomicAdd(&nbr_sum[s4.w], nw[n4.w]);
}

__global__ void __launch_bounds__(256)
fixup_nosum(float* __restrict__ nbr_sum) {
    const int i = blockIdx.x * 256 + threadIdx.x;
    if (i < NUM_NODES && nbr_sum[i] == 0.f) nbr_sum[i] = 1.0f;
}

extern "C" void kernel_launch(void* const* d_in, const int* in_sizes, int n_in,
                              void* d_out, int out_size, void* d_ws, size_t ws_size,
                              hipStream_t stream) {
    const float* x            = (const float*)d_in[0];
    const int*   bags         = (const int*)d_in[1];
    const float* alpha        = (const float*)d_in[2];
    const int*   edge_src     = (const int*)d_in[3];
    const int*   edge_nbr     = (const int*)d_in[4];
    const float* node_weights = (const float*)d_in[5];
    const float* theta        = (const float*)d_in[6];
    float*       out          = (float*)d_out;

    // ws layout: w[3.2M] f32 | rep[NSLICE][100000] f32 | nbr_sum | h
    const size_t need4 =
        ((size_t)N_EDGES + (size_t)NSLICE4 * NUM_NODES + 2 * (size_t)NUM_NODES) * 4;
    const size_t need8 =
        ((size_t)N_EDGES + (size_t)NSLICE8 * NUM_NODES + 2 * (size_t)NUM_NODES) * 4;

    // Raise the dynamic-LDS cap for hist4 (host-side attr, capture-safe).
    const hipError_t attr_ok = hipFuncSetAttribute(
        (const void*)hist4, hipFuncAttributeMaxDynamicSharedMemorySize,
        NPP4 * (int)sizeof(float));

    if (attr_ok == hipSuccess && ws_size >= need4) {
        float* w       = (float*)d_ws;
        float* rep     = w + N_EDGES;
        float* nbr_sum = rep + (size_t)NSLICE4 * NUM_NODES;
        float* h       = nbr_sum + NUM_NODES;

        mat_w<<<NQUAD / 256, 256, 0, stream>>>(edge_nbr, node_weights, w);
        hist4<<<4 * NSLICE4, 1024, NPP4 * sizeof(float), stream>>>(edge_src, w, rep);
        reduce_rep<NSLICE4><<<(NUM_NODES + 255) / 256, 256, 0, stream>>>(rep, nbr_sum);
        gemv_h<<<2048, 256, 0, stream>>>(x, theta, h);
        bag_final<<<NUM_BAGS / 4, 256, 0, stream>>>(bags, alpha, h, nbr_sum, out);
    } else if (ws_size >= need8) {
        float* w       = (float*)d_ws;
        float* rep     = w + N_EDGES;
        float* nbr_sum = rep + (size_t)NSLICE8 * NUM_NODES;
        float* h       = nbr_sum + NUM_NODES;

        mat_w<<<NQUAD / 256, 256, 0, stream>>>(edge_nbr, node_weights, w);
        hist8<<<8 * NSLICE8, 1024, 0, stream>>>(edge_src, w, rep);
        reduce_rep<NSLICE8><<<(NUM_NODES + 255) / 256, 256, 0, stream>>>(rep, nbr_sum);
        gemv_h<<<2048, 256, 0, stream>>>(x, theta, h);
        bag_final<<<NUM_BAGS / 4, 256, 0, stream>>>(bags, alpha, h, nbr_sum, out);
    } else {
        // Tiny-ws fallback: device atomics (needs 800 KB).
        float* nbr_sum = (float*)d_ws;
        float* h       = nbr_sum + NUM_NODES;
        hipMemsetAsync(nbr_sum, 0, (size_t)NUM_NODES * 4, stream);
        edge_atomic<<<(N_EDGES / 4) / 256, 256, 0, stream>>>(
            edge_src, edge_nbr, node_weights, nbr_sum);
        fixup_nosum<<<(NUM_NODES + 255) / 256, 256, 0, stream>>>(nbr_sum);
        gemv_h<<<2048, 256, 0, stream>>>(x, theta, h);
        bag_final<<<NUM_BAGS / 4, 256, 0, stream>>>(bags, alpha, h, nbr_sum, out);
    }
}